// Round 1
// baseline (57.036 us; speedup 1.0000x reference)
//
#include <hip/hip_runtime.h>
#include <math.h>

// Closed-form matrix log for CSO affine matrices M = [[s*R, t],[0,1]]:
//   L = [[log(s)*I + log(R), psi(L3)*t],[0,0]],  psi(x)=x/(e^x - 1)
// then project onto the orthonormal CSO basis analytically.

__global__ __launch_bounds__(256) void affine_log_kernel(
    const float* __restrict__ aff, float* __restrict__ out, int batch)
{
    int b = blockIdx.x * blockDim.x + threadIdx.x;
    if (b >= batch) return;

    // Load the 4x4 row-major matrix (last row is [0,0,0,1], unused).
    const float4* p = reinterpret_cast<const float4*>(aff) + (size_t)b * 4;
    float4 r0 = p[0];
    float4 r1 = p[1];
    float4 r2 = p[2];

    double A00 = r0.x, A01 = r0.y, A02 = r0.z, t0 = r0.w;
    double A10 = r1.x, A11 = r1.y, A12 = r1.z, t1 = r1.w;
    double A20 = r2.x, A21 = r2.y, A22 = r2.z, t2 = r2.w;

    // Isotropic scale: A = s*R with R orthonormal => ||A||_F^2 = 3 s^2.
    double fro = A00*A00 + A01*A01 + A02*A02
               + A10*A10 + A11*A11 + A12*A12
               + A20*A20 + A21*A21 + A22*A22;
    double s2    = fro * (1.0 / 3.0);
    double ls    = 0.5 * log(s2);      // log(s)
    double inv_s = rsqrt(s2);          // 1/s

    // Rotation log (Rodrigues). R = A/s.
    double trR = (A00 + A11 + A22) * inv_s;
    double cth = 0.5 * (trR - 1.0);
    cth = fmin(1.0, fmax(-1.0, cth));
    double theta = acos(cth);
    double th2 = theta * theta;
    double f;  // theta / (2 sin theta)
    if (theta < 1e-2) {
        // 0.5 * theta/sin(theta) = 0.5*(1 + th2/6 + 7 th2^2/360 + ...)
        f = 0.5 + th2 * (1.0 / 12.0) + th2 * th2 * (7.0 / 720.0);
    } else {
        f = theta / (2.0 * sin(theta));
    }
    double w01 = f * (A01 - A10) * inv_s;
    double w02 = f * (A02 - A20) * inv_s;
    double w12 = f * (A12 - A21) * inv_s;

    // L = log(s)*I + log(R)  (3x3 block of the full log)
    double L[3][3] = {
        {  ls,  w01,  w02 },
        { -w01,  ls,  w12 },
        { -w02, -w12,  ls }
    };

    // psi(L) = I - L/2 + L^2/12 - L^4/720 + L^6/30240  (Bernoulli series)
    double L2m[3][3], L4m[3][3], L6m[3][3];
#pragma unroll
    for (int i = 0; i < 3; ++i)
#pragma unroll
        for (int j = 0; j < 3; ++j) {
            double acc = 0.0;
#pragma unroll
            for (int k = 0; k < 3; ++k) acc += L[i][k] * L[k][j];
            L2m[i][j] = acc;
        }
#pragma unroll
    for (int i = 0; i < 3; ++i)
#pragma unroll
        for (int j = 0; j < 3; ++j) {
            double acc = 0.0;
#pragma unroll
            for (int k = 0; k < 3; ++k) acc += L2m[i][k] * L2m[k][j];
            L4m[i][j] = acc;
        }
#pragma unroll
    for (int i = 0; i < 3; ++i)
#pragma unroll
        for (int j = 0; j < 3; ++j) {
            double acc = 0.0;
#pragma unroll
            for (int k = 0; k < 3; ++k) acc += L4m[i][k] * L2m[k][j];
            L6m[i][j] = acc;
        }

    double psi[3][3];
#pragma unroll
    for (int i = 0; i < 3; ++i)
#pragma unroll
        for (int j = 0; j < 3; ++j) {
            double d = (i == j) ? 1.0 : 0.0;
            psi[i][j] = d - 0.5 * L[i][j]
                      + (1.0 / 12.0)   * L2m[i][j]
                      - (1.0 / 720.0)  * L4m[i][j]
                      + (1.0 / 30240.0) * L6m[i][j];
        }

    // Translation part of the log: v = psi(L) * t
    double v0 = psi[0][0] * t0 + psi[0][1] * t1 + psi[0][2] * t2;
    double v1 = psi[1][0] * t0 + psi[1][1] * t1 + psi[1][2] * t2;
    double v2 = psi[2][0] * t0 + psi[2][1] * t1 + psi[2][2] * t2;

    // Project onto the CSO basis:
    //   out[0..2] = v (translations, basis entry 1 at (i,3))
    //   out[3..5] = (L[i][j]-L[j][i])/sqrt(2) = sqrt(2)*w_ij for (0,1),(0,2),(1,2)
    //   out[6]    = trace(L)/sqrt(3) = 3*ls/sqrt(3) = sqrt(3)*ls
    const double SQRT2 = 1.4142135623730951;
    const double SQRT3 = 1.7320508075688772;
    float* o = out + (size_t)b * 7;
    o[0] = (float)v0;
    o[1] = (float)v1;
    o[2] = (float)v2;
    o[3] = (float)(w01 * SQRT2);
    o[4] = (float)(w02 * SQRT2);
    o[5] = (float)(w12 * SQRT2);
    o[6] = (float)(ls * SQRT3);
}

extern "C" void kernel_launch(void* const* d_in, const int* in_sizes, int n_in,
                              void* d_out, int out_size, void* d_ws, size_t ws_size,
                              hipStream_t stream) {
    const float* aff = (const float*)d_in[0];
    float* out = (float*)d_out;
    int batch = in_sizes[0] / 16;  // 65536 matrices of 4x4
    int block = 256;
    int grid = (batch + block - 1) / block;
    affine_log_kernel<<<grid, block, 0, stream>>>(aff, out, batch);
}

// Round 2
// 55.719 us; speedup vs baseline: 1.0236x; 1.0236x over previous
//
#include <hip/hip_runtime.h>
#include <math.h>

// Closed-form matrix log for CSO affine matrices M = [[s*R, t],[0,1]]:
//   L = [[log(s)*I + log(R), psi(L3)*t],[0,0]],  psi(x)=x/(e^x - 1)
// projected analytically onto the orthonormal CSO basis.
// All-f32: comparison floor is bf16 (~1e-3); f32 closed form is ~1e-5 accurate.

__global__ __launch_bounds__(256) void affine_log_kernel(
    const float* __restrict__ aff, float* __restrict__ out, int batch)
{
    int b = blockIdx.x * blockDim.x + threadIdx.x;
    if (b >= batch) return;

    // Load the 4x4 row-major matrix (last row is [0,0,0,1], unused).
    const float4* p = reinterpret_cast<const float4*>(aff) + (size_t)b * 4;
    float4 r0 = p[0];
    float4 r1 = p[1];
    float4 r2 = p[2];

    float A00 = r0.x, A01 = r0.y, A02 = r0.z, t0 = r0.w;
    float A10 = r1.x, A11 = r1.y, A12 = r1.z, t1 = r1.w;
    float A20 = r2.x, A21 = r2.y, A22 = r2.z, t2 = r2.w;

    // Isotropic scale: A = s*R, R orthonormal => ||A||_F^2 = 3 s^2.
    float fro = A00*A00 + A01*A01 + A02*A02
              + A10*A10 + A11*A11 + A12*A12
              + A20*A20 + A21*A21 + A22*A22;
    float s2    = fro * (1.0f / 3.0f);
    float ls    = 0.5f * __logf(s2);   // log(s)
    float inv_s = rsqrtf(s2);          // 1/s

    // Rotation log (Rodrigues). R = A/s.
    float trR = (A00 + A11 + A22) * inv_s;
    float cth = 0.5f * (trR - 1.0f);
    cth = fminf(1.0f, fmaxf(-1.0f, cth));
    float theta = acosf(cth);
    float th2 = theta * theta;
    float f;  // theta / (2 sin theta)
    if (theta < 1e-2f) {
        f = 0.5f + th2 * (1.0f / 12.0f) + th2 * th2 * (7.0f / 720.0f);
    } else {
        f = theta / (2.0f * __sinf(theta));
    }
    float w01 = f * (A01 - A10) * inv_s;
    float w02 = f * (A02 - A20) * inv_s;
    float w12 = f * (A12 - A21) * inv_s;

    // L = log(s)*I + log(R)  (3x3 block of the full log)
    float L[3][3] = {
        {  ls,  w01,  w02 },
        { -w01,  ls,  w12 },
        { -w02, -w12,  ls }
    };

    // psi(L) = I - L/2 + L^2/12 - L^4/720 + L^6/30240  (Bernoulli series)
    float L2m[3][3], L4m[3][3], L6m[3][3];
#pragma unroll
    for (int i = 0; i < 3; ++i)
#pragma unroll
        for (int j = 0; j < 3; ++j) {
            float acc = 0.0f;
#pragma unroll
            for (int k = 0; k < 3; ++k) acc += L[i][k] * L[k][j];
            L2m[i][j] = acc;
        }
#pragma unroll
    for (int i = 0; i < 3; ++i)
#pragma unroll
        for (int j = 0; j < 3; ++j) {
            float acc = 0.0f;
#pragma unroll
            for (int k = 0; k < 3; ++k) acc += L2m[i][k] * L2m[k][j];
            L4m[i][j] = acc;
        }
#pragma unroll
    for (int i = 0; i < 3; ++i)
#pragma unroll
        for (int j = 0; j < 3; ++j) {
            float acc = 0.0f;
#pragma unroll
            for (int k = 0; k < 3; ++k) acc += L4m[i][k] * L2m[k][j];
            L6m[i][j] = acc;
        }

    float psi[3][3];
#pragma unroll
    for (int i = 0; i < 3; ++i)
#pragma unroll
        for (int j = 0; j < 3; ++j) {
            float d = (i == j) ? 1.0f : 0.0f;
            psi[i][j] = d - 0.5f * L[i][j]
                      + (1.0f / 12.0f)    * L2m[i][j]
                      - (1.0f / 720.0f)   * L4m[i][j]
                      + (1.0f / 30240.0f) * L6m[i][j];
        }

    // Translation part of the log: v = psi(L) * t
    float v0 = psi[0][0] * t0 + psi[0][1] * t1 + psi[0][2] * t2;
    float v1 = psi[1][0] * t0 + psi[1][1] * t1 + psi[1][2] * t2;
    float v2 = psi[2][0] * t0 + psi[2][1] * t1 + psi[2][2] * t2;

    // Project onto the CSO basis:
    //   out[0..2] = v; out[3..5] = sqrt(2)*w_ij for (0,1),(0,2),(1,2);
    //   out[6] = trace(L)/sqrt(3) = sqrt(3)*log(s)
    const float SQRT2 = 1.41421356237f;
    const float SQRT3 = 1.73205080757f;
    float* o = out + (size_t)b * 7;
    o[0] = v0;
    o[1] = v1;
    o[2] = v2;
    o[3] = w01 * SQRT2;
    o[4] = w02 * SQRT2;
    o[5] = w12 * SQRT2;
    o[6] = ls * SQRT3;
}

extern "C" void kernel_launch(void* const* d_in, const int* in_sizes, int n_in,
                              void* d_out, int out_size, void* d_ws, size_t ws_size,
                              hipStream_t stream) {
    const float* aff = (const float*)d_in[0];
    float* out = (float*)d_out;
    int batch = in_sizes[0] / 16;  // 65536 matrices of 4x4
    int block = 256;
    int grid = (batch + block - 1) / block;
    affine_log_kernel<<<grid, block, 0, stream>>>(aff, out, batch);
}